// Round 1
// baseline (593.879 us; speedup 1.0000x reference)
//
#include <hip/hip_runtime.h>
#include <math.h>

#define C_DIM 512
#define T_DIM 1024
#define BATCH 8
#define NHEAD 8
#define CH 64

// ---------------------------------------------------------------------------
// GroupNorm: one block per (batch, group). group = 16 channels x 1024 t.
// ---------------------------------------------------------------------------
__global__ __launch_bounds__(256) void gn_kernel(const float* __restrict__ x,
                                                 const float* __restrict__ gamma,
                                                 const float* __restrict__ beta,
                                                 float* __restrict__ h) {
    int bg = blockIdx.x;
    int b = bg >> 5, g = bg & 31;
    const float* xp = x + ((size_t)(b * C_DIM + g * 16)) * T_DIM;
    float* hp = h + ((size_t)(b * C_DIM + g * 16)) * T_DIM;
    int tid = threadIdx.x;

    float s = 0.f, ss = 0.f;
    // 16*1024 floats = 4096 float4, 16 per thread
    for (int r = 0; r < 16; ++r) {
        int idx = r * 256 + tid;
        float4 v = ((const float4*)xp)[idx];
        s  += v.x + v.y + v.z + v.w;
        ss += v.x * v.x + v.y * v.y + v.z * v.z + v.w * v.w;
    }
    // wave64 reduce
    for (int off = 32; off > 0; off >>= 1) {
        s  += __shfl_down(s, off, 64);
        ss += __shfl_down(ss, off, 64);
    }
    __shared__ float rs[4], rss[4], stat[2];
    int wave = tid >> 6;
    if ((tid & 63) == 0) { rs[wave] = s; rss[wave] = ss; }
    __syncthreads();
    if (tid == 0) {
        float S  = rs[0] + rs[1] + rs[2] + rs[3];
        float SS = rss[0] + rss[1] + rss[2] + rss[3];
        float mean = S * (1.f / 16384.f);
        float var  = SS * (1.f / 16384.f) - mean * mean;
        stat[0] = mean;
        stat[1] = rsqrtf(var + 1e-5f);
    }
    __syncthreads();
    float mean = stat[0], rstd = stat[1];
    for (int r = 0; r < 16; ++r) {
        int idx = r * 256 + tid;
        int cl = idx >> 8;  // (idx*4)/1024
        float gm = gamma[g * 16 + cl] * rstd;
        float bt = beta[g * 16 + cl];
        float4 v = ((const float4*)xp)[idx];
        float4 o;
        o.x = (v.x - mean) * gm + bt;
        o.y = (v.y - mean) * gm + bt;
        o.z = (v.z - mean) * gm + bt;
        o.w = (v.w - mean) * gm + bt;
        ((float4*)hp)[idx] = o;
    }
}

// ---------------------------------------------------------------------------
// Batched SGEMM: out[b] = W(M,K) @ X[b](K,N) + bias (+ res[b])
// 64x64 block tile, 16-deep K tile, 256 threads, 4x4 micro-tile.
// M,N % 64 == 0, K % 16 == 0 (holds for all our shapes).
// ---------------------------------------------------------------------------
__global__ __launch_bounds__(256) void sgemm_kernel(const float* __restrict__ W,
                                                    const float* __restrict__ X,
                                                    const float* __restrict__ bias,
                                                    const float* __restrict__ res,
                                                    float* __restrict__ out,
                                                    int M, int N, int K, int has_res) {
    __shared__ float As[16][68];  // As[k][m]
    __shared__ float Bs[16][68];  // Bs[k][n]
    int tid = threadIdx.x;
    int tn0 = blockIdx.x * 64, tm0 = blockIdx.y * 64, b = blockIdx.z;
    const float* Xp = X + (size_t)b * K * N;
    float* Op = out + (size_t)b * M * N;
    int ty = tid >> 4, tx = tid & 15;

    int am = tid >> 2, akq = tid & 3;   // A loader: 64 rows x 4 float4
    int bk = tid >> 4, bnq = tid & 15;  // B loader: 16 rows x 16 float4

    float acc[4][4] = {};

    for (int k0 = 0; k0 < K; k0 += 16) {
        float4 av = *(const float4*)&W[(size_t)(tm0 + am) * K + k0 + akq * 4];
        float4 bv = *(const float4*)&Xp[(size_t)(k0 + bk) * N + tn0 + bnq * 4];
        As[akq * 4 + 0][am] = av.x;
        As[akq * 4 + 1][am] = av.y;
        As[akq * 4 + 2][am] = av.z;
        As[akq * 4 + 3][am] = av.w;
        *(float4*)&Bs[bk][bnq * 4] = bv;
        __syncthreads();
#pragma unroll
        for (int kk = 0; kk < 16; ++kk) {
            float4 a4 = *(const float4*)&As[kk][ty * 4];
            float4 b4 = *(const float4*)&Bs[kk][tx * 4];
            float ar[4] = {a4.x, a4.y, a4.z, a4.w};
            float br[4] = {b4.x, b4.y, b4.z, b4.w};
#pragma unroll
            for (int i = 0; i < 4; ++i)
#pragma unroll
                for (int j = 0; j < 4; ++j)
                    acc[i][j] += ar[i] * br[j];
        }
        __syncthreads();
    }

#pragma unroll
    for (int i = 0; i < 4; ++i) {
        int m = tm0 + ty * 4 + i;
        float bi = bias[m];
        size_t o = (size_t)m * N + tn0 + tx * 4;
        float4 v = make_float4(acc[i][0] + bi, acc[i][1] + bi,
                               acc[i][2] + bi, acc[i][3] + bi);
        if (has_res) {
            float4 rv = *(const float4*)&res[(size_t)b * M * N + o];
            v.x += rv.x; v.y += rv.y; v.z += rv.z; v.w += rv.w;
        }
        *(float4*)&Op[o] = v;
    }
}

// ---------------------------------------------------------------------------
// Flash attention: one block per (q-tile of 64, batch*head).
// qkv layout: (b, 1536, t); head hd rows [hd*192, hd*192+192) = q|k|v.
// Online softmax; scores scaled by 1/sqrt(ch) = 0.125 (== scale^2 exactly).
// ---------------------------------------------------------------------------
__global__ __launch_bounds__(256) void attn_kernel(const float* __restrict__ qkv,
                                                   float* __restrict__ a_out) {
    __shared__ float Qs[64][68];  // Qs[c][i]
    __shared__ float Ks[64][68];  // Ks[c][j]  (re-used as Ps[j][i] after S compute)
    __shared__ float Vs[64][68];  // Vs[c][j]
    __shared__ float alpha_s[64];
    __shared__ float linv_s[64];
    float (*Ps)[68] = Ks;

    int tid = threadIdx.x;
    int q0 = blockIdx.x * 64;
    int bh = blockIdx.y;
    int b = bh >> 3, hd = bh & 7;
    const float* base = qkv + (size_t)b * 1536 * T_DIM + (size_t)hd * 192 * T_DIM;
    const float* Qp = base;
    const float* Kp = base + (size_t)64 * T_DIM;
    const float* Vp = base + (size_t)128 * T_DIM;

    // load Q tile: Qs[c][i] = Q[c][q0+i]
    for (int r = 0; r < 4; ++r) {
        int fl = r * 256 + tid;
        int c = fl >> 4, i4 = fl & 15;
        *(float4*)&Qs[c][i4 * 4] = *(const float4*)&Qp[(size_t)c * T_DIM + q0 + i4 * 4];
    }

    int ty = tid >> 4, tx = tid & 15;
    float acc_o[4][4] = {};            // [ii][cc], i = tx*4+ii, c = ty*4+cc
    float m_r = -INFINITY, l_r = 0.f;  // live in threads tid<64 (row = tid)

    for (int s0 = 0; s0 < T_DIM; s0 += 64) {
        // load K,V tiles
        for (int r = 0; r < 4; ++r) {
            int fl = r * 256 + tid;
            int c = fl >> 4, i4 = fl & 15;
            *(float4*)&Ks[c][i4 * 4] = *(const float4*)&Kp[(size_t)c * T_DIM + s0 + i4 * 4];
            *(float4*)&Vs[c][i4 * 4] = *(const float4*)&Vp[(size_t)c * T_DIM + s0 + i4 * 4];
        }
        __syncthreads();

        // S[i][j], i = ty*4+ii, j = tx*4+jj
        float s_acc[4][4] = {};
#pragma unroll 8
        for (int c = 0; c < 64; ++c) {
            float4 q4 = *(const float4*)&Qs[c][ty * 4];
            float4 k4 = *(const float4*)&Ks[c][tx * 4];
            float qa[4] = {q4.x, q4.y, q4.z, q4.w};
            float ka[4] = {k4.x, k4.y, k4.z, k4.w};
#pragma unroll
            for (int ii = 0; ii < 4; ++ii)
#pragma unroll
                for (int jj = 0; jj < 4; ++jj)
                    s_acc[ii][jj] += qa[ii] * ka[jj];
        }
        __syncthreads();  // everyone done reading Ks/Qs; Ks becomes Ps

        // write S^T * 0.125 into Ps[j][i]
#pragma unroll
        for (int jj = 0; jj < 4; ++jj) {
            float4 v = make_float4(s_acc[0][jj] * 0.125f, s_acc[1][jj] * 0.125f,
                                   s_acc[2][jj] * 0.125f, s_acc[3][jj] * 0.125f);
            *(float4*)&Ps[tx * 4 + jj][ty * 4] = v;
        }
        __syncthreads();

        // online softmax, one thread per query row
        if (tid < 64) {
            int i = tid;
            float mx = -INFINITY;
            for (int j = 0; j < 64; ++j) mx = fmaxf(mx, Ps[j][i]);
            float m_new = fmaxf(m_r, mx);
            float alpha = __expf(m_r - m_new);
            float sum = 0.f;
            for (int j = 0; j < 64; ++j) {
                float p = __expf(Ps[j][i] - m_new);
                Ps[j][i] = p;
                sum += p;
            }
            l_r = l_r * alpha + sum;
            m_r = m_new;
            alpha_s[i] = alpha;
        }
        __syncthreads();

        // O update: O[i][c] = O[i][c]*alpha[i] + sum_j P[i][j]*V[c][j]
        float al[4];
#pragma unroll
        for (int ii = 0; ii < 4; ++ii) al[ii] = alpha_s[tx * 4 + ii];
#pragma unroll
        for (int ii = 0; ii < 4; ++ii)
#pragma unroll
            for (int cc = 0; cc < 4; ++cc) acc_o[ii][cc] *= al[ii];

#pragma unroll 4
        for (int j = 0; j < 64; ++j) {
            float4 p4 = *(const float4*)&Ps[j][tx * 4];
            float pa[4] = {p4.x, p4.y, p4.z, p4.w};
            float va[4];
#pragma unroll
            for (int cc = 0; cc < 4; ++cc) va[cc] = Vs[ty * 4 + cc][j];
#pragma unroll
            for (int ii = 0; ii < 4; ++ii)
#pragma unroll
                for (int cc = 0; cc < 4; ++cc)
                    acc_o[ii][cc] += pa[ii] * va[cc];
        }
        __syncthreads();  // before next tile overwrites Ks/Vs
    }

    if (tid < 64) linv_s[tid] = 1.f / l_r;
    __syncthreads();
    float li[4];
#pragma unroll
    for (int ii = 0; ii < 4; ++ii) li[ii] = linv_s[tx * 4 + ii];

    float* ap = a_out + (size_t)b * C_DIM * T_DIM + (size_t)(hd * CH) * T_DIM;
#pragma unroll
    for (int cc = 0; cc < 4; ++cc) {
        int c = ty * 4 + cc;
        float4 v = make_float4(acc_o[0][cc] * li[0], acc_o[1][cc] * li[1],
                               acc_o[2][cc] * li[2], acc_o[3][cc] * li[3]);
        *(float4*)&ap[(size_t)c * T_DIM + q0 + tx * 4] = v;
    }
}

// ---------------------------------------------------------------------------
extern "C" void kernel_launch(void* const* d_in, const int* in_sizes, int n_in,
                              void* d_out, int out_size, void* d_ws, size_t ws_size,
                              hipStream_t stream) {
    (void)in_sizes; (void)n_in; (void)out_size; (void)ws_size;
    const float* x      = (const float*)d_in[0];
    const float* gamma  = (const float*)d_in[1];
    const float* beta   = (const float*)d_in[2];
    const float* w_qkv  = (const float*)d_in[3];
    const float* b_qkv  = (const float*)d_in[4];
    const float* w_proj = (const float*)d_in[5];
    const float* b_proj = (const float*)d_in[6];
    float* out = (float*)d_out;
    float* ws  = (float*)d_ws;

    float* h   = ws;                    // 8*512*1024 floats
    float* qkv = ws + (size_t)BATCH * C_DIM * T_DIM;  // 8*1536*1024 floats
    float* a   = ws;                    // reuse h space (h dead after QKV GEMM)

    gn_kernel<<<dim3(BATCH * 32), 256, 0, stream>>>(x, gamma, beta, h);

    dim3 g_qkv(T_DIM / 64, (3 * C_DIM) / 64, BATCH);
    sgemm_kernel<<<g_qkv, 256, 0, stream>>>(w_qkv, h, b_qkv, nullptr, qkv,
                                            3 * C_DIM, T_DIM, C_DIM, 0);

    dim3 g_attn(T_DIM / 64, BATCH * NHEAD);
    attn_kernel<<<g_attn, 256, 0, stream>>>(qkv, a);

    dim3 g_proj(T_DIM / 64, C_DIM / 64, BATCH);
    sgemm_kernel<<<g_proj, 256, 0, stream>>>(w_proj, a, b_proj, x, out,
                                             C_DIM, T_DIM, C_DIM, 1);
}

// Round 2
// 212.210 us; speedup vs baseline: 2.7985x; 2.7985x over previous
//
#include <hip/hip_runtime.h>
#include <hip/hip_bf16.h>
#include <math.h>

#define BATCH 8
#define CDIM 512
#define TDIM 1024
#define NHD 8

typedef __attribute__((ext_vector_type(8))) short bf16x8;
typedef __attribute__((ext_vector_type(4))) float floatx4;

static __device__ __forceinline__ unsigned short f2bf(float f) {
    __hip_bfloat16 h = __float2bfloat16(f);
    return *reinterpret_cast<unsigned short*>(&h);
}

// ---------------------------------------------------------------------------
// fp32 -> bf16 conversion (weights), 4 elements/thread
// ---------------------------------------------------------------------------
__global__ __launch_bounds__(256) void cvt_kernel(const float* __restrict__ src,
                                                  unsigned short* __restrict__ dst,
                                                  int n4) {
    int i = blockIdx.x * 256 + threadIdx.x;
    if (i >= n4) return;
    float4 v = ((const float4*)src)[i];
    ushort4 o;
    o.x = f2bf(v.x); o.y = f2bf(v.y); o.z = f2bf(v.z); o.w = f2bf(v.w);
    ((ushort4*)dst)[i] = o;
}

// ---------------------------------------------------------------------------
// GroupNorm -> h^T bf16, layout h_t[b][t][c] (c=512 contiguous).
// One block per (batch, group of 16 channels).
// ---------------------------------------------------------------------------
__global__ __launch_bounds__(256) void gn_kernel(const float* __restrict__ x,
                                                 const float* __restrict__ gamma,
                                                 const float* __restrict__ beta,
                                                 unsigned short* __restrict__ h_t) {
    int bg = blockIdx.x;
    int b = bg >> 5, g = bg & 31;
    const float* xp = x + ((size_t)(b * CDIM + g * 16)) * TDIM;
    int tid = threadIdx.x;

    float s = 0.f, ss = 0.f;
    for (int r = 0; r < 16; ++r) {
        float4 v = ((const float4*)xp)[r * 256 + tid];
        s  += v.x + v.y + v.z + v.w;
        ss += v.x * v.x + v.y * v.y + v.z * v.z + v.w * v.w;
    }
    for (int off = 32; off > 0; off >>= 1) {
        s  += __shfl_down(s, off, 64);
        ss += __shfl_down(ss, off, 64);
    }
    __shared__ float rs[4], rss[4], stat[2];
    int wave = tid >> 6;
    if ((tid & 63) == 0) { rs[wave] = s; rss[wave] = ss; }
    __syncthreads();
    if (tid == 0) {
        float S  = rs[0] + rs[1] + rs[2] + rs[3];
        float SS = rss[0] + rss[1] + rss[2] + rss[3];
        float mean = S * (1.f / 16384.f);
        float var  = SS * (1.f / 16384.f) - mean * mean;
        stat[0] = mean;
        stat[1] = rsqrtf(var + 1e-5f);
    }
    __syncthreads();
    float mean = stat[0], rstd = stat[1];

    // write phase: thread owns channel-pair (cpair) x t-stripe
    int cpair = tid & 7, trow = tid >> 3;  // 8 cpairs x 32 t-rows
    int c0 = g * 16 + cpair * 2;
    float g0 = gamma[c0] * rstd,  g1 = gamma[c0 + 1] * rstd;
    float b0 = beta[c0] - mean * g0, b1 = beta[c0 + 1] - mean * g1;
    const float* x0 = x + ((size_t)(b * CDIM + c0)) * TDIM;
    const float* x1 = x0 + TDIM;
    unsigned int* hp = (unsigned int*)h_t + (size_t)b * TDIM * 256 + g * 8 + cpair;
    for (int p = 0; p < 32; ++p) {
        int t = p * 32 + trow;
        float v0 = x0[t] * g0 + b0;
        float v1 = x1[t] * g1 + b1;
        hp[(size_t)t * 256] = (unsigned)f2bf(v0) | ((unsigned)f2bf(v1) << 16);
    }
}

// ---------------------------------------------------------------------------
// MFMA GEMM: out[m][n] = sum_k W[m][k] * Xt[n][k]  (+bias, per-mode epilogue)
// W: (M,K) bf16 row-major. Xt: per-batch (TDIM,K) bf16 row-major.
// 128x128 block tile, BK=32, 256 threads (4 waves, each 64x64).
// mode 0: QKV -> q_t (t-major, *0.125), k_t (t-major), v (c-major), bf16
// mode 1: proj -> fp32 out[b][m][n] = acc + bias + resid
// ---------------------------------------------------------------------------
__global__ __launch_bounds__(256) void mfma_gemm(
    const unsigned short* __restrict__ Wb,
    const unsigned short* __restrict__ Xt,
    const float* __restrict__ bias,
    int M, int K, int mode,
    unsigned short* __restrict__ q_t,
    unsigned short* __restrict__ k_t,
    unsigned short* __restrict__ v,
    const float* __restrict__ resid,
    float* __restrict__ outp) {
    __shared__ unsigned short As[128][40];  // [m][k], +8 pad
    __shared__ unsigned short Bs[128][40];  // [n][k], +8 pad

    int tid = threadIdx.x;
    int n0 = blockIdx.x * 128, m0 = blockIdx.y * 128, bb = blockIdx.z;
    const unsigned short* Xp = Xt + (size_t)bb * TDIM * K;

    int lane = tid & 63, wave = tid >> 6;
    int l15 = lane & 15, quad = lane >> 4;
    int wm = wave >> 1, wn = wave & 1;

    int ar = tid >> 2;            // staging row 0..63 (and +64)
    int kc = (tid & 3) * 8;       // k chunk offset in halves

    floatx4 acc[4][4];
#pragma unroll
    for (int i = 0; i < 4; ++i)
#pragma unroll
        for (int j = 0; j < 4; ++j) acc[i][j] = (floatx4){0.f, 0.f, 0.f, 0.f};

    for (int k0 = 0; k0 < K; k0 += 32) {
        __syncthreads();
        uint4 a0 = *(const uint4*)(Wb + (size_t)(m0 + ar) * K + k0 + kc);
        uint4 a1 = *(const uint4*)(Wb + (size_t)(m0 + ar + 64) * K + k0 + kc);
        uint4 b0 = *(const uint4*)(Xp + (size_t)(n0 + ar) * K + k0 + kc);
        uint4 b1 = *(const uint4*)(Xp + (size_t)(n0 + ar + 64) * K + k0 + kc);
        *(uint4*)&As[ar][kc]      = a0;
        *(uint4*)&As[ar + 64][kc] = a1;
        *(uint4*)&Bs[ar][kc]      = b0;
        *(uint4*)&Bs[ar + 64][kc] = b1;
        __syncthreads();

        bf16x8 af[4], bf[4];
#pragma unroll
        for (int mi = 0; mi < 4; ++mi)
            af[mi] = *(const bf16x8*)&As[wm * 64 + mi * 16 + l15][quad * 8];
#pragma unroll
        for (int ni = 0; ni < 4; ++ni)
            bf[ni] = *(const bf16x8*)&Bs[wn * 64 + ni * 16 + l15][quad * 8];
#pragma unroll
        for (int mi = 0; mi < 4; ++mi)
#pragma unroll
            for (int ni = 0; ni < 4; ++ni)
                acc[mi][ni] = __builtin_amdgcn_mfma_f32_16x16x32_bf16(
                    af[mi], bf[ni], acc[mi][ni], 0, 0, 0);
    }

    int b8 = bb * NHD;
#pragma unroll
    for (int mi = 0; mi < 4; ++mi) {
        int mBase = m0 + wm * 64 + mi * 16 + quad * 4;
#pragma unroll
        for (int ni = 0; ni < 4; ++ni) {
            floatx4 a = acc[mi][ni];
            int n = n0 + wn * 64 + ni * 16 + l15;
            if (mode == 0) {
                int chunk = mBase >> 6;
                int hd = chunk / 3, part = chunk % 3;
                int cB = mBase & 63;
#pragma unroll
                for (int r = 0; r < 4; ++r) {
                    float val = a[r] + bias[mBase + r];
                    int c = cB + r;
                    if (part == 0)
                        q_t[((size_t)(b8 + hd) * TDIM + n) * 64 + c] = f2bf(val * 0.125f);
                    else if (part == 1)
                        k_t[((size_t)(b8 + hd) * TDIM + n) * 64 + c] = f2bf(val);
                    else
                        v[((size_t)(b8 + hd) * 64 + c) * TDIM + n] = f2bf(val);
                }
            } else {
                size_t base = ((size_t)bb * CDIM + mBase) * TDIM + n;
#pragma unroll
                for (int r = 0; r < 4; ++r)
                    outp[base + (size_t)r * TDIM] =
                        a[r] + bias[mBase + r] + resid[base + (size_t)r * TDIM];
            }
        }
    }
}

// ---------------------------------------------------------------------------
// MFMA flash attention. Block = (q-tile 64, head). 4 waves, each 16 q-rows.
// q_t,k_t: [bh][t][c=64] bf16 (q pre-scaled by 0.125). v: [bh][c=64][t] bf16.
// Softmax fully in registers (quad-local shfl_xor). P via per-wave LDS.
// Output a_t[b][t][c=512] bf16.
// ---------------------------------------------------------------------------
__global__ __launch_bounds__(256) void attn_kernel(
    const unsigned short* __restrict__ q_t,
    const unsigned short* __restrict__ k_t,
    const unsigned short* __restrict__ v,
    unsigned short* __restrict__ a_t) {
    __shared__ unsigned short Qs[64][72];     // [i][c]
    __shared__ unsigned short Ks[64][72];     // [j][c]
    __shared__ unsigned short Vs[64][72];     // [c][j]
    __shared__ unsigned short Ps[4][16][88];  // per-wave [i][j]

    int tid = threadIdx.x;
    int q0 = blockIdx.x * 64;
    int bh = blockIdx.y;
    int lane = tid & 63, wave = tid >> 6;
    int l15 = lane & 15, quad = lane >> 4;

    const unsigned short* Qp = q_t + (size_t)bh * TDIM * 64;
    const unsigned short* Kp = k_t + (size_t)bh * TDIM * 64;
    const unsigned short* Vp = v + (size_t)bh * 64 * TDIM;

    int sr = tid >> 3;            // staging row 0..31 (and +32)
    int sc = (tid & 7) * 8;       // half-offset within 64-half row

    *(uint4*)&Qs[sr][sc]      = *(const uint4*)(Qp + (size_t)(q0 + sr) * 64 + sc);
    *(uint4*)&Qs[sr + 32][sc] = *(const uint4*)(Qp + (size_t)(q0 + sr + 32) * 64 + sc);

    floatx4 o_acc[4];
#pragma unroll
    for (int i = 0; i < 4; ++i) o_acc[i] = (floatx4){0.f, 0.f, 0.f, 0.f};
    float m_old[4] = {-INFINITY, -INFINITY, -INFINITY, -INFINITY};
    float l_old[4] = {0.f, 0.f, 0.f, 0.f};

    for (int s0 = 0; s0 < TDIM; s0 += 64) {
        __syncthreads();  // prev iter done reading Ks/Vs
        *(uint4*)&Ks[sr][sc]      = *(const uint4*)(Kp + (size_t)(s0 + sr) * 64 + sc);
        *(uint4*)&Ks[sr + 32][sc] = *(const uint4*)(Kp + (size_t)(s0 + sr + 32) * 64 + sc);
        *(uint4*)&Vs[sr][sc]      = *(const uint4*)(Vp + (size_t)sr * TDIM + s0 + sc);
        *(uint4*)&Vs[sr + 32][sc] = *(const uint4*)(Vp + (size_t)(sr + 32) * TDIM + s0 + sc);
        __syncthreads();

        // S = Q . K^T  (rows wave*16..+16, all 64 cols)
        bf16x8 aq0 = *(const bf16x8*)&Qs[wave * 16 + l15][quad * 8];
        bf16x8 aq1 = *(const bf16x8*)&Qs[wave * 16 + l15][32 + quad * 8];
        floatx4 s_acc[4];
#pragma unroll
        for (int ni = 0; ni < 4; ++ni) {
            bf16x8 bk0 = *(const bf16x8*)&Ks[ni * 16 + l15][quad * 8];
            bf16x8 bk1 = *(const bf16x8*)&Ks[ni * 16 + l15][32 + quad * 8];
            floatx4 z = (floatx4){0.f, 0.f, 0.f, 0.f};
            z = __builtin_amdgcn_mfma_f32_16x16x32_bf16(aq0, bk0, z, 0, 0, 0);
            z = __builtin_amdgcn_mfma_f32_16x16x32_bf16(aq1, bk1, z, 0, 0, 0);
            s_acc[ni] = z;
        }

        // online softmax per row r (rows replicated across the quad's 16 lanes)
        float alpha[4];
#pragma unroll
        for (int r = 0; r < 4; ++r) {
            float mx = fmaxf(fmaxf(s_acc[0][r], s_acc[1][r]),
                             fmaxf(s_acc[2][r], s_acc[3][r]));
            mx = fmaxf(mx, __shfl_xor(mx, 1));
            mx = fmaxf(mx, __shfl_xor(mx, 2));
            mx = fmaxf(mx, __shfl_xor(mx, 4));
            mx = fmaxf(mx, __shfl_xor(mx, 8));
            float mn = fmaxf(m_old[r], mx);
            float al = __expf(m_old[r] - mn);
            float p0 = __expf(s_acc[0][r] - mn);
            float p1 = __expf(s_acc[1][r] - mn);
            float p2 = __expf(s_acc[2][r] - mn);
            float p3 = __expf(s_acc[3][r] - mn);
            s_acc[0][r] = p0; s_acc[1][r] = p1; s_acc[2][r] = p2; s_acc[3][r] = p3;
            float sum = p0 + p1 + p2 + p3;
            sum += __shfl_xor(sum, 1);
            sum += __shfl_xor(sum, 2);
            sum += __shfl_xor(sum, 4);
            sum += __shfl_xor(sum, 8);
            l_old[r] = l_old[r] * al + sum;
            m_old[r] = mn;
            alpha[r] = al;
        }

        // P (C-layout) -> LDS (A-layout source), bf16
#pragma unroll
        for (int ni = 0; ni < 4; ++ni)
#pragma unroll
            for (int r = 0; r < 4; ++r)
                Ps[wave][quad * 4 + r][ni * 16 + l15] = f2bf(s_acc[ni][r]);

        // rescale O
#pragma unroll
        for (int ci = 0; ci < 4; ++ci)
#pragma unroll
            for (int r = 0; r < 4; ++r) o_acc[ci][r] *= alpha[r];

        // O += P . V^T
        bf16x8 pa0 = *(const bf16x8*)&Ps[wave][l15][quad * 8];
        bf16x8 pa1 = *(const bf16x8*)&Ps[wave][l15][32 + quad * 8];
#pragma unroll
        for (int ci = 0; ci < 4; ++ci) {
            bf16x8 vb0 = *(const bf16x8*)&Vs[ci * 16 + l15][quad * 8];
            bf16x8 vb1 = *(const bf16x8*)&Vs[ci * 16 + l15][32 + quad * 8];
            o_acc[ci] = __builtin_amdgcn_mfma_f32_16x16x32_bf16(pa0, vb0, o_acc[ci], 0, 0, 0);
            o_acc[ci] = __builtin_amdgcn_mfma_f32_16x16x32_bf16(pa1, vb1, o_acc[ci], 0, 0, 0);
        }
    }

    int b = bh >> 3, hd = bh & 7;
#pragma unroll
    for (int r = 0; r < 4; ++r) {
        float li = 1.f / l_old[r];
        int i = q0 + wave * 16 + quad * 4 + r;
        size_t rowbase = ((size_t)b * TDIM + i) * CDIM + hd * 64;
#pragma unroll
        for (int ci = 0; ci < 4; ++ci)
            a_t[rowbase + ci * 16 + l15] = f2bf(o_acc[ci][r] * li);
    }
}

// ---------------------------------------------------------------------------
extern "C" void kernel_launch(void* const* d_in, const int* in_sizes, int n_in,
                              void* d_out, int out_size, void* d_ws, size_t ws_size,
                              hipStream_t stream) {
    (void)in_sizes; (void)n_in; (void)out_size; (void)ws_size;
    const float* x      = (const float*)d_in[0];
    const float* gamma  = (const float*)d_in[1];
    const float* beta   = (const float*)d_in[2];
    const float* w_qkv  = (const float*)d_in[3];
    const float* b_qkv  = (const float*)d_in[4];
    const float* w_proj = (const float*)d_in[5];
    const float* b_proj = (const float*)d_in[6];
    float* out = (float*)d_out;

    unsigned short* wqkv_bf  = (unsigned short*)d_ws;              // 1536*512
    unsigned short* wproj_bf = wqkv_bf + 1536 * 512;               // 512*512
    unsigned short* h_t      = wproj_bf + 512 * 512;               // 8*1024*512
    unsigned short* q_t      = h_t + (size_t)BATCH * TDIM * CDIM;  // 64*1024*64
    unsigned short* k_t      = q_t + (size_t)64 * TDIM * 64;
    unsigned short* vv       = k_t + (size_t)64 * TDIM * 64;
    unsigned short* a_t      = vv + (size_t)64 * TDIM * 64;        // 8*1024*512

    cvt_kernel<<<768, 256, 0, stream>>>(w_qkv, wqkv_bf, 1536 * 512 / 4);
    cvt_kernel<<<256, 256, 0, stream>>>(w_proj, wproj_bf, 512 * 512 / 4);

    gn_kernel<<<BATCH * 32, 256, 0, stream>>>(x, gamma, beta, h_t);

    mfma_gemm<<<dim3(8, 12, BATCH), 256, 0, stream>>>(
        wqkv_bf, h_t, b_qkv, 1536, 512, 0, q_t, k_t, vv, nullptr, nullptr);

    attn_kernel<<<dim3(16, 64), 256, 0, stream>>>(q_t, k_t, vv, a_t);

    mfma_gemm<<<dim3(8, 4, BATCH), 256, 0, stream>>>(
        wproj_bf, a_t, b_proj, 512, 512, 1, nullptr, nullptr, nullptr, x, out);
}

// Round 3
// 178.777 us; speedup vs baseline: 3.3219x; 1.1870x over previous
//
#include <hip/hip_runtime.h>
#include <hip/hip_bf16.h>
#include <math.h>

#define BATCH 8
#define CDIM 512
#define TDIM 1024
#define NHD 8

typedef __attribute__((ext_vector_type(8))) short bf16x8;
typedef __attribute__((ext_vector_type(8))) _Float16 f16x8;
typedef __attribute__((ext_vector_type(4))) float floatx4;

#define QSCALE 0.18033688011112042f  // 0.125 * log2(e)

static __device__ __forceinline__ unsigned short f2bf(float f) {
    __hip_bfloat16 h = __float2bfloat16(f);
    return *reinterpret_cast<unsigned short*>(&h);
}
static __device__ __forceinline__ unsigned short f2h(float f) {
    _Float16 h = (_Float16)f;
    return *reinterpret_cast<unsigned short*>(&h);
}
// async global->LDS, 16B per lane; lds dest = wave-uniform base + lane*16
static __device__ __forceinline__ void async_load16(const unsigned short* gsrc,
                                                    unsigned short* ldst) {
    __builtin_amdgcn_global_load_lds(
        (const __attribute__((address_space(1))) void*)gsrc,
        (__attribute__((address_space(3))) void*)ldst, 16, 0, 0);
}

// ---------------------------------------------------------------------------
// fp32 -> bf16 weight conversion, both weights in one launch
// ---------------------------------------------------------------------------
__global__ __launch_bounds__(256) void cvt2_kernel(const float* __restrict__ a,
                                                   const float* __restrict__ b,
                                                   unsigned short* __restrict__ da,
                                                   unsigned short* __restrict__ db) {
    int i = blockIdx.x * 256 + threadIdx.x;
    const int nA = 1536 * 512 / 4;
    const float* s;
    unsigned short* d;
    int j;
    if (i < nA) { s = a; d = da; j = i; }
    else        { s = b; d = db; j = i - nA; }
    float4 v = ((const float4*)s)[j];
    ushort4 o;
    o.x = f2bf(v.x); o.y = f2bf(v.y); o.z = f2bf(v.z); o.w = f2bf(v.w);
    ((ushort4*)d)[j] = o;
}

// ---------------------------------------------------------------------------
// GroupNorm -> h^T bf16, layout h_t[b][t][c] (c=512 contiguous).
// ---------------------------------------------------------------------------
__global__ __launch_bounds__(256) void gn_kernel(const float* __restrict__ x,
                                                 const float* __restrict__ gamma,
                                                 const float* __restrict__ beta,
                                                 unsigned short* __restrict__ h_t) {
    int bg = blockIdx.x;
    int b = bg >> 5, g = bg & 31;
    const float* xp = x + ((size_t)(b * CDIM + g * 16)) * TDIM;
    int tid = threadIdx.x;

    float s = 0.f, ss = 0.f;
    for (int r = 0; r < 16; ++r) {
        float4 v = ((const float4*)xp)[r * 256 + tid];
        s  += v.x + v.y + v.z + v.w;
        ss += v.x * v.x + v.y * v.y + v.z * v.z + v.w * v.w;
    }
    for (int off = 32; off > 0; off >>= 1) {
        s  += __shfl_down(s, off, 64);
        ss += __shfl_down(ss, off, 64);
    }
    __shared__ float rs[4], rss[4], stat[2];
    int wave = tid >> 6;
    if ((tid & 63) == 0) { rs[wave] = s; rss[wave] = ss; }
    __syncthreads();
    if (tid == 0) {
        float S  = rs[0] + rs[1] + rs[2] + rs[3];
        float SS = rss[0] + rss[1] + rss[2] + rss[3];
        float mean = S * (1.f / 16384.f);
        float var  = SS * (1.f / 16384.f) - mean * mean;
        stat[0] = mean;
        stat[1] = rsqrtf(var + 1e-5f);
    }
    __syncthreads();
    float mean = stat[0], rstd = stat[1];

    int cpair = tid & 7, trow = tid >> 3;  // 8 lanes span 8 cpairs of one t -> 32B segs
    int c0 = g * 16 + cpair * 2;
    float g0 = gamma[c0] * rstd,  g1 = gamma[c0 + 1] * rstd;
    float b0 = beta[c0] - mean * g0, b1 = beta[c0 + 1] - mean * g1;
    const float* x0 = x + ((size_t)(b * CDIM + c0)) * TDIM;
    const float* x1 = x0 + TDIM;
    unsigned int* hp = (unsigned int*)h_t + (size_t)b * TDIM * 256 + g * 8 + cpair;
    for (int p = 0; p < 32; ++p) {
        int t = p * 32 + trow;
        float v0 = x0[t] * g0 + b0;
        float v1 = x1[t] * g1 + b1;
        hp[(size_t)t * 256] = (unsigned)f2bf(v0) | ((unsigned)f2bf(v1) << 16);
    }
}

// ---------------------------------------------------------------------------
// MFMA GEMM (m97 pattern): 128x128 tile, BK=32, async global->LDS staging,
// unpadded [128][32] LDS. mode 0: QKV -> q_t/k_t (t-major f16, q*QSCALE),
// v (c-major f16). mode 1: fp32 out = acc + bias + resid.
// ---------------------------------------------------------------------------
__global__ __launch_bounds__(256) void mfma_gemm(
    const unsigned short* __restrict__ Wb,
    const unsigned short* __restrict__ Xt,
    const float* __restrict__ bias,
    int M, int K, int mode,
    unsigned short* __restrict__ q_t,
    unsigned short* __restrict__ k_t,
    unsigned short* __restrict__ v,
    const float* __restrict__ resid,
    float* __restrict__ outp) {
    __shared__ __align__(16) unsigned short As[128 * 32];
    __shared__ __align__(16) unsigned short Bs[128 * 32];

    int tid = threadIdx.x;
    int n0 = blockIdx.x * 128, m0 = blockIdx.y * 128, bb = blockIdx.z;
    const unsigned short* Xp = Xt + (size_t)bb * TDIM * K;

    int lane = tid & 63, w = tid >> 6;
    int l15 = lane & 15, quad = lane >> 4;
    int wm = w >> 1, wn = w & 1;

    // async staging slots: slot s (16B = row s>>2, kgroup s&3); wave w covers
    // slots [w*128, w*128+128) via 2 instructions (c=0,1)
    int s0i = w * 128 + lane;
    int rA0 = s0i >> 2, gA0 = s0i & 3;
    int rA1 = (s0i + 64) >> 2, gA1 = (s0i + 64) & 3;
    const unsigned short* aS0 = Wb + (size_t)(m0 + rA0) * K + gA0 * 8;
    const unsigned short* aS1 = Wb + (size_t)(m0 + rA1) * K + gA1 * 8;
    const unsigned short* bS0 = Xp + (size_t)(n0 + rA0) * K + gA0 * 8;
    const unsigned short* bS1 = Xp + (size_t)(n0 + rA1) * K + gA1 * 8;
    unsigned short* aD0 = &As[(w * 128) * 8];
    unsigned short* aD1 = &As[(w * 128 + 64) * 8];
    unsigned short* bD0 = &Bs[(w * 128) * 8];
    unsigned short* bD1 = &Bs[(w * 128 + 64) * 8];

    floatx4 acc[4][4];
#pragma unroll
    for (int i = 0; i < 4; ++i)
#pragma unroll
        for (int j = 0; j < 4; ++j) acc[i][j] = (floatx4){0.f, 0.f, 0.f, 0.f};

    for (int k0 = 0; k0 < K; k0 += 32) {
        async_load16(aS0 + k0, aD0);
        async_load16(aS1 + k0, aD1);
        async_load16(bS0 + k0, bD0);
        async_load16(bS1 + k0, bD1);
        __syncthreads();

        bf16x8 af[4], bfr[4];
#pragma unroll
        for (int mi = 0; mi < 4; ++mi)
            af[mi] = *(const bf16x8*)&As[(wm * 64 + mi * 16 + l15) * 32 + quad * 8];
#pragma unroll
        for (int ni = 0; ni < 4; ++ni)
            bfr[ni] = *(const bf16x8*)&Bs[(wn * 64 + ni * 16 + l15) * 32 + quad * 8];
#pragma unroll
        for (int mi = 0; mi < 4; ++mi)
#pragma unroll
            for (int ni = 0; ni < 4; ++ni)
                acc[mi][ni] = __builtin_amdgcn_mfma_f32_16x16x32_bf16(
                    af[mi], bfr[ni], acc[mi][ni], 0, 0, 0);
        __syncthreads();
    }

    int b8 = bb * NHD;
#pragma unroll
    for (int mi = 0; mi < 4; ++mi) {
        int mBase = m0 + wm * 64 + mi * 16 + quad * 4;
#pragma unroll
        for (int ni = 0; ni < 4; ++ni) {
            floatx4 a = acc[mi][ni];
            int n = n0 + wn * 64 + ni * 16 + l15;
            if (mode == 0) {
                int chunk = mBase >> 6;
                int hd = chunk / 3, part = chunk % 3;
                int cB = mBase & 63;
#pragma unroll
                for (int r = 0; r < 4; ++r) {
                    float val = a[r] + bias[mBase + r];
                    int c = cB + r;
                    if (part == 0)
                        q_t[((size_t)(b8 + hd) * TDIM + n) * 64 + c] = f2h(val * QSCALE);
                    else if (part == 1)
                        k_t[((size_t)(b8 + hd) * TDIM + n) * 64 + c] = f2h(val);
                    else
                        v[((size_t)(b8 + hd) * 64 + c) * TDIM + n] = f2h(val);
                }
            } else {
                size_t base = ((size_t)bb * CDIM + mBase) * TDIM + n;
#pragma unroll
                for (int r = 0; r < 4; ++r)
                    outp[base + (size_t)r * TDIM] =
                        a[r] + bias[mBase + r] + resid[base + (size_t)r * TDIM];
            }
        }
    }
}

// ---------------------------------------------------------------------------
// MFMA flash attention, S^T form. Block = (64 q-rows, one bh); 4 waves,
// wave w owns q rows w*16..w*16+16; each lane owns ONE query (i = lane&15).
// K staged with row permutation so post-softmax P registers are already in
// 16x16x32 B-operand layout (no LDS roundtrip for P).
// LDS: unpadded 64x64 f16 tiles, 3-bit XOR group swizzle, async staging.
// ---------------------------------------------------------------------------
__global__ __launch_bounds__(256, 4) void attn_kernel(
    const unsigned short* __restrict__ q_t,  // f16 [bh][t][64], pre-scaled
    const unsigned short* __restrict__ k_t,  // f16 [bh][t][64]
    const unsigned short* __restrict__ v,    // f16 [bh][c=64][t]
    unsigned short* __restrict__ a_t) {      // bf16 [b][t][512]
    __shared__ __align__(16) unsigned short Qs[64 * 64];
    __shared__ __align__(16) unsigned short Ks[64 * 64];
    __shared__ __align__(16) unsigned short Vs[64 * 64];

    int tid = threadIdx.x;
    int q0 = blockIdx.x * 64;
    int bh = blockIdx.y;
    int lane = tid & 63, w = tid >> 6;
    int l15 = lane & 15, quad = lane >> 4;
    int l7 = l15 & 7;

    const unsigned short* Qp = q_t + (size_t)bh * TDIM * 64;
    const unsigned short* Kp = k_t + (size_t)bh * TDIM * 64;
    const unsigned short* Vp = v + (size_t)bh * 64 * TDIM;

    // stage Q once: element (r, col) at r*64 + ((col>>3)^(r&7))*8 + (col&7)
#pragma unroll
    for (int it = 0; it < 2; ++it) {
        int s = it * 256 + tid;
        int r = s >> 3, gs = s & 7, g = gs ^ (r & 7);
        *(uint4*)&Qs[s * 8] = *(const uint4*)(Qp + (size_t)(q0 + r) * 64 + g * 8);
    }

    // per-lane async source offsets for K (permuted rows) and V
    int kofs[2], vofs[2];
    unsigned short *kdst[2], *vdst[2];
#pragma unroll
    for (int c = 0; c < 2; ++c) {
        int s = w * 128 + c * 64 + lane;
        int m = s >> 3, gs = s & 7, g = gs ^ (m & 7);
        int mi = m >> 4, qq = (m >> 2) & 3, rr = m & 3;
        int pm = (mi & 1) * 32 + qq * 8 + (mi >> 1) * 4 + rr;  // permuted key row
        kofs[c] = pm * 64 + g * 8;   // + s0*64
        vofs[c] = m * TDIM + g * 8;  // + s0
        kdst[c] = &Ks[(w * 128 + c * 64) * 8];
        vdst[c] = &Vs[(w * 128 + c * 64) * 8];
    }

    __syncthreads();  // Q visible
    int myrow = w * 16 + l15;
    f16x8 qf[2];
#pragma unroll
    for (int ch = 0; ch < 2; ++ch)
        qf[ch] = *(const f16x8*)&Qs[myrow * 64 + ((ch * 4 + quad) ^ l7) * 8];

    floatx4 o_acc[4];
#pragma unroll
    for (int i = 0; i < 4; ++i) o_acc[i] = (floatx4){0.f, 0.f, 0.f, 0.f};
    float m_run = -INFINITY, l_run = 0.f;

    for (int s0 = 0; s0 < TDIM; s0 += 64) {
        async_load16(Kp + (size_t)s0 * 64 + kofs[0], kdst[0]);
        async_load16(Kp + (size_t)s0 * 64 + kofs[1], kdst[1]);
        async_load16(Vp + s0 + vofs[0], vdst[0]);
        async_load16(Vp + s0 + vofs[1], vdst[1]);
        __syncthreads();  // staging landed (vmcnt drained by barrier)

        // S^T = K . Q^T : D[m = staged key row][n = query i = l15]
        floatx4 sT[4];
#pragma unroll
        for (int mi = 0; mi < 4; ++mi) {
            int row = mi * 16 + l15;
            f16x8 k0 = *(const f16x8*)&Ks[row * 64 + ((0 + quad) ^ l7) * 8];
            f16x8 k1 = *(const f16x8*)&Ks[row * 64 + ((4 + quad) ^ l7) * 8];
            floatx4 z = (floatx4){0.f, 0.f, 0.f, 0.f};
            z = __builtin_amdgcn_mfma_f32_16x16x32_f16(k0, qf[0], z, 0, 0, 0);
            z = __builtin_amdgcn_mfma_f32_16x16x32_f16(k1, qf[1], z, 0, 0, 0);
            sT[mi] = z;
        }

        // online softmax: lane owns query i=l15; scores replicated over quads
        float mx = sT[0][0];
#pragma unroll
        for (int mi = 0; mi < 4; ++mi)
#pragma unroll
            for (int r = 0; r < 4; ++r) mx = fmaxf(mx, sT[mi][r]);
        mx = fmaxf(mx, __shfl_xor(mx, 16));
        mx = fmaxf(mx, __shfl_xor(mx, 32));
        float mn = fmaxf(m_run, mx);
        float alpha = __builtin_amdgcn_exp2f(m_run - mn);
        float sum = 0.f;
#pragma unroll
        for (int mi = 0; mi < 4; ++mi)
#pragma unroll
            for (int r = 0; r < 4; ++r) {
                float p = __builtin_amdgcn_exp2f(sT[mi][r] - mn);
                sT[mi][r] = p;
                sum += p;
            }
        sum += __shfl_xor(sum, 16);
        sum += __shfl_xor(sum, 32);
        l_run = l_run * alpha + sum;
        m_run = mn;

        // P registers -> B-operand fragments (pure repack, perm makes it line up:
        // key j of sT[mi][r] = s0 + 32*(mi&1) + 8*quad + 4*(mi>>1) + r)
        f16x8 pf[2];
#pragma unroll
        for (int kb = 0; kb < 2; ++kb) {
            pf[kb][0] = (_Float16)sT[kb][0];
            pf[kb][1] = (_Float16)sT[kb][1];
            pf[kb][2] = (_Float16)sT[kb][2];
            pf[kb][3] = (_Float16)sT[kb][3];
            pf[kb][4] = (_Float16)sT[kb + 2][0];
            pf[kb][5] = (_Float16)sT[kb + 2][1];
            pf[kb][6] = (_Float16)sT[kb + 2][2];
            pf[kb][7] = (_Float16)sT[kb + 2][3];
        }

        // rescale O, then O^T += V . P^T  : D[m = c][n = i]
#pragma unroll
        for (int ci = 0; ci < 4; ++ci) {
            o_acc[ci][0] *= alpha; o_acc[ci][1] *= alpha;
            o_acc[ci][2] *= alpha; o_acc[ci][3] *= alpha;
        }
#pragma unroll
        for (int ci = 0; ci < 4; ++ci) {
            int row = ci * 16 + l15;
#pragma unroll
            for (int kb = 0; kb < 2; ++kb) {
                f16x8 vf = *(const f16x8*)&Vs[row * 64 + ((kb * 4 + quad) ^ l7) * 8];
                o_acc[ci] = __builtin_amdgcn_mfma_f32_16x16x32_f16(vf, pf[kb], o_acc[ci], 0, 0, 0);
            }
        }
        __syncthreads();  // done reading Ks/Vs before next overwrite
    }

    // epilogue: normalize, transpose via LDS (reuse Ks), coalesced bf16 store
    float linv = 1.f / l_run;
#pragma unroll
    for (int ci = 0; ci < 4; ++ci) {
        ushort4 pk;
        pk.x = f2bf(o_acc[ci][0] * linv);
        pk.y = f2bf(o_acc[ci][1] * linv);
        pk.z = f2bf(o_acc[ci][2] * linv);
        pk.w = f2bf(o_acc[ci][3] * linv);
        int col = ci * 16 + quad * 4;  // 4 consecutive c
        int gs = (col >> 3) ^ l7;
        *(ushort4*)&Ks[myrow * 64 + gs * 8 + (quad & 1) * 4] = pk;
    }
    __syncthreads();
    int b = bh >> 3, hd = bh & 7;
    size_t obase = ((size_t)b * TDIM + q0) * CDIM + hd * 64;
#pragma unroll
    for (int it = 0; it < 2; ++it) {
        int s = it * 256 + tid;
        int r = s >> 3, gs = s & 7, g = gs ^ (r & 7);
        *(uint4*)(a_t + obase + (size_t)r * CDIM + g * 8) = *(const uint4*)&Ks[s * 8];
    }
}

// ---------------------------------------------------------------------------
extern "C" void kernel_launch(void* const* d_in, const int* in_sizes, int n_in,
                              void* d_out, int out_size, void* d_ws, size_t ws_size,
                              hipStream_t stream) {
    (void)in_sizes; (void)n_in; (void)out_size; (void)ws_size;
    const float* x      = (const float*)d_in[0];
    const float* gamma  = (const float*)d_in[1];
    const float* beta   = (const float*)d_in[2];
    const float* w_qkv  = (const float*)d_in[3];
    const float* b_qkv  = (const float*)d_in[4];
    const float* w_proj = (const float*)d_in[5];
    const float* b_proj = (const float*)d_in[6];
    float* out = (float*)d_out;

    unsigned short* wqkv_bf  = (unsigned short*)d_ws;              // 1536*512
    unsigned short* wproj_bf = wqkv_bf + 1536 * 512;               // 512*512
    unsigned short* h_t      = wproj_bf + 512 * 512;               // 8*1024*512 bf16
    unsigned short* q_t      = h_t + (size_t)BATCH * TDIM * CDIM;  // f16 64*1024*64
    unsigned short* k_t      = q_t + (size_t)64 * TDIM * 64;
    unsigned short* vv       = k_t + (size_t)64 * TDIM * 64;
    unsigned short* a_t      = vv + (size_t)64 * TDIM * 64;        // bf16 8*1024*512

    cvt2_kernel<<<(1536 * 512 + 512 * 512) / 1024, 256, 0, stream>>>(
        w_qkv, w_proj, wqkv_bf, wproj_bf);

    gn_kernel<<<BATCH * 32, 256, 0, stream>>>(x, gamma, beta, h_t);

    mfma_gemm<<<dim3(8, 12, BATCH), 256, 0, stream>>>(
        wqkv_bf, h_t, b_qkv, 1536, 512, 0, q_t, k_t, vv, nullptr, nullptr);

    attn_kernel<<<dim3(16, 64), 256, 0, stream>>>(q_t, k_t, vv, a_t);

    mfma_gemm<<<dim3(8, 4, BATCH), 256, 0, stream>>>(
        wproj_bf, a_t, b_proj, 512, 512, 1, nullptr, nullptr, nullptr, x, out);
}